// Round 2
// baseline (906.981 us; speedup 1.0000x reference)
//
#include <hip/hip_runtime.h>
#include <math.h>

// ---------------- problem constants ----------------
constexpr int BATCH  = 2;
constexpr int CDIM   = 96;    // model dim
constexpr int HH     = 56;
constexpr int WW     = 56;
constexpr int LL     = HH * WW;          // 3136
constexpr int DIN    = 192;              // d_inner
constexpr int NK     = 4;                // directions
constexpr int NST    = 16;               // d_state
constexpr int RNK    = 6;                // dt_rank
constexpr int EPROJ  = RNK + 2 * NST;    // 38

// workspace layout (floats)
constexpr size_t SZ_PX   = (size_t)BATCH * LL * DIN;        // 1,204,224
constexpr size_t OFF_XP  = 0;
constexpr size_t OFF_Z   = OFF_XP + SZ_PX;
constexpr size_t OFF_XI  = OFF_Z  + SZ_PX;
constexpr size_t OFF_DL  = OFF_XI + SZ_PX;                  // delta: K*B*L*192
constexpr size_t SZ_DL   = (size_t)NK * BATCH * LL * DIN;
constexpr size_t OFF_B   = OFF_DL + SZ_DL;                  // B: K*B*L*16
constexpr size_t SZ_BC   = (size_t)NK * BATCH * LL * NST;
constexpr size_t OFF_C   = OFF_B + SZ_BC;
constexpr size_t OFF_Y   = OFF_C + SZ_BC;                   // ysum: B*L*192

__device__ __forceinline__ float silu(float v) {
    return v / (1.0f + __expf(-v));
}

// direction k, sequence position l -> row-major spatial index
__device__ __forceinline__ int seq_to_lr(int k, int l) {
    int q = l / WW;
    int r = l - q * WW;
    if (k == 0) return l;
    if (k == 1) return q * WW + (WW - 1 - r);
    if (k == 2) return r * WW + q;
    return (WW - 1 - r) * WW + q;
}

// direction k, row-major spatial index s -> sequence position (inverse map)
__device__ __forceinline__ int spatial_to_seq(int k, int s) {
    int h = s / WW;
    int w = s - h * WW;
    if (k == 0) return s;
    if (k == 1) return h * WW + (WW - 1 - w);
    if (k == 2) return w * WW + h;
    return w * WW + (WW - 1 - h);
}

// ---------------- kernel 1: in-projection (x^T @ W_in -> xp, z) --------------
constexpr int K1_PIX = 8;
__global__ __launch_bounds__(384) void k_inproj(
        const float* __restrict__ x, const float* __restrict__ W_in,
        float* __restrict__ xp, float* __restrict__ z) {
    __shared__ float sx[K1_PIX][100];   // padded to break bank conflicts
    int gp0 = blockIdx.x * K1_PIX;      // global pixel = b*LL + l
    int t   = threadIdx.x;
    int b   = gp0 / LL;
    int l0  = gp0 - b * LL;
    for (int i = t; i < K1_PIX * CDIM; i += 384) {
        int p = i % K1_PIX;
        int c = i / K1_PIX;
        sx[p][c] = x[((size_t)(b * CDIM + c)) * LL + l0 + p];
    }
    __syncthreads();
    int e = t;                          // 0..383 output feature
    float acc[K1_PIX];
#pragma unroll
    for (int p = 0; p < K1_PIX; p++) acc[p] = 0.0f;
    for (int c = 0; c < CDIM; c++) {
        float w = W_in[c * (2 * DIN) + e];
#pragma unroll
        for (int p = 0; p < K1_PIX; p++) acc[p] = fmaf(sx[p][c], w, acc[p]);
    }
    if (e < DIN) {
#pragma unroll
        for (int p = 0; p < K1_PIX; p++)
            xp[((size_t)(gp0 + p)) * DIN + e] = acc[p];
    } else {
        int e2 = e - DIN;
#pragma unroll
        for (int p = 0; p < K1_PIX; p++)
            z[((size_t)(gp0 + p)) * DIN + e2] = acc[p];
    }
}

// ---------------- kernel 2: depthwise conv 3x3 + bias + SiLU ----------------
__global__ __launch_bounds__(192) void k_conv(
        const float* __restrict__ xp, const float* __restrict__ Wc,
        const float* __restrict__ bc, float* __restrict__ xi) {
    int gp = blockIdx.x;
    int d  = threadIdx.x;
    int b  = gp / LL;
    int l  = gp - b * LL;
    int h  = l / WW;
    int w  = l - h * WW;
    float acc = bc[d];
#pragma unroll
    for (int dy = -1; dy <= 1; dy++) {
        int hh = h + dy;
        if (hh < 0 || hh >= HH) continue;
#pragma unroll
        for (int dx = -1; dx <= 1; dx++) {
            int ww = w + dx;
            if (ww < 0 || ww >= WW) continue;
            acc = fmaf(xp[((size_t)b * LL + hh * WW + ww) * DIN + d],
                       Wc[d * 9 + (dy + 1) * 3 + (dx + 1)], acc);
        }
    }
    xi[(size_t)gp * DIN + d] = silu(acc);
}

// ------- kernel 3: x-proj (dr,B,C) + delta=softplus(dr@W_dt+b) + ysum=0 ------
// Each block handles K3_PIX *spatial* pixels; results are scattered to the
// direction-k *sequence* position via spatial_to_seq (the round-1 bug fix).
constexpr int K3_PIX = 8;
__global__ __launch_bounds__(256) void k_xproj(
        const float* __restrict__ xi, const float* __restrict__ W_xproj,
        const float* __restrict__ W_dt, const float* __restrict__ b_dt,
        float* __restrict__ dbuf, float* __restrict__ Bbuf,
        float* __restrict__ Cbuf, float* __restrict__ ysum) {
    __shared__ float v[K3_PIX][DIN];
    __shared__ float drs[K3_PIX][RNK];
    int k   = blockIdx.y;
    int gp0 = blockIdx.x * K3_PIX;
    int b   = gp0 / LL;
    int l0  = gp0 - b * LL;
    int t   = threadIdx.x;
    for (int i = t; i < K3_PIX * DIN; i += 256) {
        int p = i / DIN, d = i % DIN;
        v[p][d] = xi[((size_t)(gp0 + p)) * DIN + d];
    }
    __syncthreads();
    for (int i = t; i < K3_PIX * EPROJ; i += 256) {
        int p = i / EPROJ, e = i % EPROJ;
        const float* wp = W_xproj + (size_t)k * DIN * EPROJ + e;
        float acc = 0.0f;
        for (int d = 0; d < DIN; d++) acc = fmaf(v[p][d], wp[d * EPROJ], acc);
        int ls = spatial_to_seq(k, l0 + p);      // sequence position
        size_t base = ((size_t)(k * BATCH + b)) * LL + ls;
        if (e < RNK)            drs[p][e] = acc;
        else if (e < RNK + NST) Bbuf[base * NST + (e - RNK)] = acc;
        else                    Cbuf[base * NST + (e - RNK - NST)] = acc;
    }
    __syncthreads();
    for (int i = t; i < K3_PIX * DIN; i += 256) {
        int p = i / DIN, d = i % DIN;
        float acc = b_dt[k * DIN + d];
#pragma unroll
        for (int r = 0; r < RNK; r++)
            acc = fmaf(drs[p][r], W_dt[((size_t)k * RNK + r) * DIN + d], acc);
        float sp = (acc > 20.0f) ? acc : log1pf(__expf(acc));
        int ls = spatial_to_seq(k, l0 + p);      // sequence position
        dbuf[(((size_t)(k * BATCH + b)) * LL + ls) * DIN + d] = sp;
        if (k == 0) ysum[((size_t)(gp0 + p)) * DIN + d] = 0.0f;
    }
}

// ---------------- kernel 4: selective scan (4 directions) --------------------
constexpr int SCH = 64;          // steps per LDS chunk (3136 % 64 == 0)
constexpr int CGRP = DIN / 16;   // 12 channel-groups of 16
__global__ __launch_bounds__(256) void k_scan(
        const float* __restrict__ xi, const float* __restrict__ dbuf,
        const float* __restrict__ Bbuf, const float* __restrict__ Cbuf,
        const float* __restrict__ A_logs, const float* __restrict__ Ds,
        float* __restrict__ ysum) {
    __shared__ float sD[SCH][16];
    __shared__ float sU[SCH][16];
    __shared__ float sB[SCH][16];
    __shared__ float sC[SCH][16];
    __shared__ float sY[SCH][16];
    int blk = blockIdx.x;
    int k   = blk / (BATCH * CGRP);
    int rem = blk % (BATCH * CGRP);
    int b   = rem / CGRP;
    int cg  = rem % CGRP;
    int d0  = cg * 16;
    int t    = threadIdx.x;
    int lane = t & 63, wave = t >> 6;
    int grp  = lane >> 4, n = lane & 15;
    int ch   = wave * 4 + grp;       // channel within block: 0..15
    int d    = d0 + ch;
    float A   = -__expf(A_logs[((size_t)(k * DIN + d)) * NST + n]);
    float Dsk = Ds[k * DIN + d];
    float h   = 0.0f;
    size_t sbase = ((size_t)(k * BATCH + b)) * LL;
    const float* dp = dbuf + sbase * DIN + d0;
    const float* bp = Bbuf + sbase * NST;
    const float* cp = Cbuf + sbase * NST;
    const float* up = xi   + (size_t)b * LL * DIN;
    float*       yp = ysum + (size_t)b * LL * DIN;

    for (int l0 = 0; l0 < LL; l0 += SCH) {
        for (int i = t; i < SCH * 16; i += 256) {
            int s = i >> 4, c = i & 15;
            int l = l0 + s;
            int lr = seq_to_lr(k, l);
            sD[s][c] = dp[(size_t)l * DIN + c];
            sU[s][c] = up[(size_t)lr * DIN + d0 + c];
            sB[s][c] = bp[(size_t)l * NST + c];
            sC[s][c] = cp[(size_t)l * NST + c];
        }
        __syncthreads();
#pragma unroll 4
        for (int s = 0; s < SCH; s++) {
            float dlt = sD[s][ch];
            float u   = sU[s][ch];
            float dA  = __expf(dlt * A);
            h = fmaf(dA, h, dlt * u * sB[s][n]);
            float p = h * sC[s][n];
            p += __shfl_xor(p, 1, 16);
            p += __shfl_xor(p, 2, 16);
            p += __shfl_xor(p, 4, 16);
            p += __shfl_xor(p, 8, 16);
            if (n == 0) sY[s][ch] = p + u * Dsk;
        }
        __syncthreads();
        for (int i = t; i < SCH * 16; i += 256) {
            int s = i >> 4, c = i & 15;
            int lr = seq_to_lr(k, l0 + s);
            atomicAdd(&yp[(size_t)lr * DIN + d0 + c], sY[s][c]);
        }
    }
}

// ---------------- kernel 5: gate + out-projection ---------------------------
__global__ __launch_bounds__(128) void k_out(
        const float* __restrict__ ysum, const float* __restrict__ zbuf,
        const float* __restrict__ W_out, float* __restrict__ out) {
    __shared__ float g[DIN];
    int gp = blockIdx.x;
    int t  = threadIdx.x;
    int b  = gp / LL;
    int l  = gp - b * LL;
    for (int i = t; i < DIN; i += 128) {
        float zv = zbuf[(size_t)gp * DIN + i];
        g[i] = ysum[(size_t)gp * DIN + i] * silu(zv);
    }
    __syncthreads();
    if (t < CDIM) {
        float acc = 0.0f;
        for (int dd = 0; dd < DIN; dd++)
            acc = fmaf(g[dd], W_out[dd * CDIM + t], acc);
        out[((size_t)(b * CDIM + t)) * LL + l] = acc;
    }
}

// ---------------- launch ----------------------------------------------------
extern "C" void kernel_launch(void* const* d_in, const int* in_sizes, int n_in,
                              void* d_out, int out_size, void* d_ws, size_t ws_size,
                              hipStream_t stream) {
    const float* x       = (const float*)d_in[0];
    const float* W_in    = (const float*)d_in[1];
    const float* W_conv  = (const float*)d_in[2];
    const float* b_conv  = (const float*)d_in[3];
    const float* W_xproj = (const float*)d_in[4];
    const float* W_dt    = (const float*)d_in[5];
    const float* b_dt    = (const float*)d_in[6];
    const float* A_logs  = (const float*)d_in[7];
    const float* Ds      = (const float*)d_in[8];
    const float* W_out   = (const float*)d_in[9];
    float* out = (float*)d_out;
    float* ws  = (float*)d_ws;

    float* xp   = ws + OFF_XP;
    float* z    = ws + OFF_Z;
    float* xi   = ws + OFF_XI;
    float* dbuf = ws + OFF_DL;
    float* Bbuf = ws + OFF_B;
    float* Cbuf = ws + OFF_C;
    float* ysum = ws + OFF_Y;

    k_inproj<<<(BATCH * LL) / K1_PIX, 384, 0, stream>>>(x, W_in, xp, z);
    k_conv<<<BATCH * LL, DIN, 0, stream>>>(xp, W_conv, b_conv, xi);
    dim3 g3((BATCH * LL) / K3_PIX, NK);
    k_xproj<<<g3, 256, 0, stream>>>(xi, W_xproj, W_dt, b_dt, dbuf, Bbuf, Cbuf, ysum);
    k_scan<<<NK * BATCH * CGRP, 256, 0, stream>>>(xi, dbuf, Bbuf, Cbuf, A_logs, Ds, ysum);
    k_out<<<BATCH * LL, 128, 0, stream>>>(ysum, z, W_out, out);
}

// Round 3
// 299.147 us; speedup vs baseline: 3.0319x; 3.0319x over previous
//
#include <hip/hip_runtime.h>
#include <math.h>

// ---------------- problem constants ----------------
constexpr int BATCH  = 2;
constexpr int CDIM   = 96;    // model dim
constexpr int HH     = 56;
constexpr int WW     = 56;
constexpr int LL     = HH * WW;          // 3136
constexpr int DIN    = 192;              // d_inner
constexpr int NK     = 4;                // directions
constexpr int NST    = 16;               // d_state
constexpr int RNK    = 6;                // dt_rank
constexpr int EPROJ  = RNK + 2 * NST;    // 38
constexpr int SCH    = 64;               // steps per scan chunk
constexpr int NCH    = LL / SCH;         // 49 chunks
constexpr int CGRP   = DIN / 16;         // 12 channel-groups of 16

// workspace layout (floats)
constexpr size_t SZ_PX   = (size_t)BATCH * LL * DIN;        // 1,204,224
constexpr size_t OFF_XP  = 0;                               // xp; reused as P after conv
constexpr size_t OFF_Z   = OFF_XP + SZ_PX;
constexpr size_t OFF_XI  = OFF_Z  + SZ_PX;
constexpr size_t OFF_DL  = OFF_XI + SZ_PX;                  // delta: K*B*L*192
constexpr size_t SZ_DL   = (size_t)NK * BATCH * LL * DIN;
constexpr size_t OFF_B   = OFF_DL + SZ_DL;                  // B: K*B*L*16
constexpr size_t SZ_BC   = (size_t)NK * BATCH * LL * NST;
constexpr size_t OFF_C   = OFF_B + SZ_BC;
constexpr size_t OFF_Y   = OFF_C + SZ_BC;                   // ysum: B*L*192
constexpr size_t SZ_HS   = (size_t)NK * BATCH * NCH * DIN * NST;  // 1,204,224
constexpr size_t OFF_HE  = OFF_Y + SZ_PX;                   // h_end per chunk
constexpr size_t OFF_HI  = OFF_HE + SZ_HS;                  // h_in  per chunk

__device__ __forceinline__ float silu(float v) {
    return v / (1.0f + __expf(-v));
}

// direction k, sequence position l -> row-major spatial index
__device__ __forceinline__ int seq_to_lr(int k, int l) {
    int q = l / WW;
    int r = l - q * WW;
    if (k == 0) return l;
    if (k == 1) return q * WW + (WW - 1 - r);
    if (k == 2) return r * WW + q;
    return (WW - 1 - r) * WW + q;
}

// direction k, row-major spatial index s -> sequence position (inverse map)
__device__ __forceinline__ int spatial_to_seq(int k, int s) {
    int h = s / WW;
    int w = s - h * WW;
    if (k == 0) return s;
    if (k == 1) return h * WW + (WW - 1 - w);
    if (k == 2) return w * WW + h;
    return w * WW + (WW - 1 - h);
}

// chunk-summary index: [c][kb][d][n], coalesced in (d,n) for pass B
__device__ __forceinline__ size_t hs_idx(int c, int kb, int d, int n) {
    return ((size_t)(c * (NK * BATCH) + kb) * DIN + d) * NST + n;
}

// ---------------- kernel 1: in-projection (x^T @ W_in -> xp, z) --------------
constexpr int K1_PIX = 8;
__global__ __launch_bounds__(384) void k_inproj(
        const float* __restrict__ x, const float* __restrict__ W_in,
        float* __restrict__ xp, float* __restrict__ z) {
    __shared__ float sx[K1_PIX][100];   // padded to break bank conflicts
    int gp0 = blockIdx.x * K1_PIX;      // global pixel = b*LL + l
    int t   = threadIdx.x;
    int b   = gp0 / LL;
    int l0  = gp0 - b * LL;
    for (int i = t; i < K1_PIX * CDIM; i += 384) {
        int p = i % K1_PIX;
        int c = i / K1_PIX;
        sx[p][c] = x[((size_t)(b * CDIM + c)) * LL + l0 + p];
    }
    __syncthreads();
    int e = t;                          // 0..383 output feature
    float acc[K1_PIX];
#pragma unroll
    for (int p = 0; p < K1_PIX; p++) acc[p] = 0.0f;
    for (int c = 0; c < CDIM; c++) {
        float w = W_in[c * (2 * DIN) + e];
#pragma unroll
        for (int p = 0; p < K1_PIX; p++) acc[p] = fmaf(sx[p][c], w, acc[p]);
    }
    if (e < DIN) {
#pragma unroll
        for (int p = 0; p < K1_PIX; p++)
            xp[((size_t)(gp0 + p)) * DIN + e] = acc[p];
    } else {
        int e2 = e - DIN;
#pragma unroll
        for (int p = 0; p < K1_PIX; p++)
            z[((size_t)(gp0 + p)) * DIN + e2] = acc[p];
    }
}

// ---------------- kernel 2: depthwise conv 3x3 + bias + SiLU ----------------
__global__ __launch_bounds__(192) void k_conv(
        const float* __restrict__ xp, const float* __restrict__ Wc,
        const float* __restrict__ bc, float* __restrict__ xi) {
    int gp = blockIdx.x;
    int d  = threadIdx.x;
    int b  = gp / LL;
    int l  = gp - b * LL;
    int h  = l / WW;
    int w  = l - h * WW;
    float acc = bc[d];
#pragma unroll
    for (int dy = -1; dy <= 1; dy++) {
        int hh = h + dy;
        if (hh < 0 || hh >= HH) continue;
#pragma unroll
        for (int dx = -1; dx <= 1; dx++) {
            int ww = w + dx;
            if (ww < 0 || ww >= WW) continue;
            acc = fmaf(xp[((size_t)b * LL + hh * WW + ww) * DIN + d],
                       Wc[d * 9 + (dy + 1) * 3 + (dx + 1)], acc);
        }
    }
    xi[(size_t)gp * DIN + d] = silu(acc);
}

// ------- kernel 3: x-proj (dr,B,C) + delta=softplus(dr@W_dt+b) + ysum=0 ------
constexpr int K3_PIX = 8;
__global__ __launch_bounds__(256) void k_xproj(
        const float* __restrict__ xi, const float* __restrict__ W_xproj,
        const float* __restrict__ W_dt, const float* __restrict__ b_dt,
        float* __restrict__ dbuf, float* __restrict__ Bbuf,
        float* __restrict__ Cbuf, float* __restrict__ ysum) {
    __shared__ float v[K3_PIX][DIN];
    __shared__ float drs[K3_PIX][RNK];
    int k   = blockIdx.y;
    int gp0 = blockIdx.x * K3_PIX;
    int b   = gp0 / LL;
    int l0  = gp0 - b * LL;
    int t   = threadIdx.x;
    for (int i = t; i < K3_PIX * DIN; i += 256) {
        int p = i / DIN, d = i % DIN;
        v[p][d] = xi[((size_t)(gp0 + p)) * DIN + d];
    }
    __syncthreads();
    for (int i = t; i < K3_PIX * EPROJ; i += 256) {
        int p = i / EPROJ, e = i % EPROJ;
        const float* wp = W_xproj + (size_t)k * DIN * EPROJ + e;
        float acc = 0.0f;
        for (int d = 0; d < DIN; d++) acc = fmaf(v[p][d], wp[d * EPROJ], acc);
        int ls = spatial_to_seq(k, l0 + p);      // sequence position
        size_t base = ((size_t)(k * BATCH + b)) * LL + ls;
        if (e < RNK)            drs[p][e] = acc;
        else if (e < RNK + NST) Bbuf[base * NST + (e - RNK)] = acc;
        else                    Cbuf[base * NST + (e - RNK - NST)] = acc;
    }
    __syncthreads();
    for (int i = t; i < K3_PIX * DIN; i += 256) {
        int p = i / DIN, d = i % DIN;
        float acc = b_dt[k * DIN + d];
#pragma unroll
        for (int r = 0; r < RNK; r++)
            acc = fmaf(drs[p][r], W_dt[((size_t)k * RNK + r) * DIN + d], acc);
        float sp = (acc > 20.0f) ? acc : log1pf(__expf(acc));
        int ls = spatial_to_seq(k, l0 + p);      // sequence position
        dbuf[(((size_t)(k * BATCH + b)) * LL + ls) * DIN + d] = sp;
        if (k == 0) ysum[((size_t)(gp0 + p)) * DIN + d] = 0.0f;
    }
}

// -------- kernel 4a: chunk-local scan -> per-chunk summary (P, h_end) --------
// block = (chunk c, kbcg); 16 channels x 16 states = 256 threads
__global__ __launch_bounds__(256) void k_scanA(
        const float* __restrict__ xi, const float* __restrict__ dbuf,
        const float* __restrict__ Bbuf, const float* __restrict__ A_logs,
        float* __restrict__ Pbuf, float* __restrict__ hend) {
    __shared__ float sD[SCH][16];
    __shared__ float sU[SCH][16];
    __shared__ float sB[SCH][16];
    int c   = blockIdx.x;
    int blk = blockIdx.y;
    int k   = blk / (BATCH * CGRP);
    int rem = blk % (BATCH * CGRP);
    int b   = rem / CGRP;
    int cg  = rem % CGRP;
    int d0  = cg * 16;
    int t    = threadIdx.x;
    int lane = t & 63, wave = t >> 6;
    int grp  = lane >> 4, n = lane & 15;
    int ch   = wave * 4 + grp;
    int d    = d0 + ch;
    float A = -__expf(A_logs[((size_t)(k * DIN + d)) * NST + n]);
    size_t sbase = ((size_t)(k * BATCH + b)) * LL;
    const float* dp = dbuf + sbase * DIN + d0;
    const float* bp = Bbuf + sbase * NST;
    const float* up = xi   + (size_t)b * LL * DIN;
    int l0 = c * SCH;
    for (int i = t; i < SCH * 16; i += 256) {
        int s = i >> 4, cc = i & 15;
        int l = l0 + s;
        int lr = seq_to_lr(k, l);
        sD[s][cc] = dp[(size_t)l * DIN + cc];
        sU[s][cc] = up[(size_t)lr * DIN + d0 + cc];
        sB[s][cc] = bp[(size_t)l * NST + cc];
    }
    __syncthreads();
    float h = 0.0f, P = 1.0f;
#pragma unroll 8
    for (int s = 0; s < SCH; s++) {
        float dlt = sD[s][ch];
        float u   = sU[s][ch];
        float dA  = __expf(dlt * A);
        h = fmaf(dA, h, dlt * u * sB[s][n]);
        P *= dA;
    }
    size_t idx = hs_idx(c, k * BATCH + b, d, n);
    Pbuf[idx] = P;
    hend[idx] = h;
}

// -------- kernel 4b: sequential combine over 49 chunk summaries --------------
__global__ __launch_bounds__(256) void k_scanB(
        const float* __restrict__ Pbuf, const float* __restrict__ hend,
        float* __restrict__ hin) {
    int tid = blockIdx.x * 256 + threadIdx.x;       // over K*B*DIN*NST = 24576
    int kb  = tid / (DIN * NST);
    int dn  = tid % (DIN * NST);
    float h = 0.0f;
    for (int c = 0; c < NCH; c++) {
        size_t idx = ((size_t)(c * (NK * BATCH) + kb)) * (DIN * NST) + dn;
        hin[idx] = h;
        h = fmaf(Pbuf[idx], h, hend[idx]);
    }
}

// -------- kernel 4c: chunk-local scan with true h_in; emit y -----------------
__global__ __launch_bounds__(256) void k_scanC(
        const float* __restrict__ xi, const float* __restrict__ dbuf,
        const float* __restrict__ Bbuf, const float* __restrict__ Cbuf,
        const float* __restrict__ A_logs, const float* __restrict__ Ds,
        const float* __restrict__ hin, float* __restrict__ ysum) {
    __shared__ float sD[SCH][16];
    __shared__ float sU[SCH][16];
    __shared__ float sB[SCH][16];
    __shared__ float sC[SCH][16];
    __shared__ float sY[SCH][16];
    int c   = blockIdx.x;
    int blk = blockIdx.y;
    int k   = blk / (BATCH * CGRP);
    int rem = blk % (BATCH * CGRP);
    int b   = rem / CGRP;
    int cg  = rem % CGRP;
    int d0  = cg * 16;
    int t    = threadIdx.x;
    int lane = t & 63, wave = t >> 6;
    int grp  = lane >> 4, n = lane & 15;
    int ch   = wave * 4 + grp;
    int d    = d0 + ch;
    float A   = -__expf(A_logs[((size_t)(k * DIN + d)) * NST + n]);
    float Dsk = Ds[k * DIN + d];
    size_t sbase = ((size_t)(k * BATCH + b)) * LL;
    const float* dp = dbuf + sbase * DIN + d0;
    const float* bp = Bbuf + sbase * NST;
    const float* cp = Cbuf + sbase * NST;
    const float* up = xi   + (size_t)b * LL * DIN;
    float*       yp = ysum + (size_t)b * LL * DIN;
    int l0 = c * SCH;
    for (int i = t; i < SCH * 16; i += 256) {
        int s = i >> 4, cc = i & 15;
        int l = l0 + s;
        int lr = seq_to_lr(k, l);
        sD[s][cc] = dp[(size_t)l * DIN + cc];
        sU[s][cc] = up[(size_t)lr * DIN + d0 + cc];
        sB[s][cc] = bp[(size_t)l * NST + cc];
        sC[s][cc] = cp[(size_t)l * NST + cc];
    }
    float h = hin[hs_idx(c, k * BATCH + b, d, n)];
    __syncthreads();
#pragma unroll 4
    for (int s = 0; s < SCH; s++) {
        float dlt = sD[s][ch];
        float u   = sU[s][ch];
        float dA  = __expf(dlt * A);
        h = fmaf(dA, h, dlt * u * sB[s][n]);
        float p = h * sC[s][n];
        p += __shfl_xor(p, 1, 16);
        p += __shfl_xor(p, 2, 16);
        p += __shfl_xor(p, 4, 16);
        p += __shfl_xor(p, 8, 16);
        if (n == 0) sY[s][ch] = p + u * Dsk;
    }
    __syncthreads();
    for (int i = t; i < SCH * 16; i += 256) {
        int s = i >> 4, cc = i & 15;
        int lr = seq_to_lr(k, l0 + s);
        atomicAdd(&yp[(size_t)lr * DIN + d0 + cc], sY[s][cc]);
    }
}

// ---------------- kernel 5: gate + out-projection ---------------------------
__global__ __launch_bounds__(128) void k_out(
        const float* __restrict__ ysum, const float* __restrict__ zbuf,
        const float* __restrict__ W_out, float* __restrict__ out) {
    __shared__ float g[DIN];
    int gp = blockIdx.x;
    int t  = threadIdx.x;
    int b  = gp / LL;
    int l  = gp - b * LL;
    for (int i = t; i < DIN; i += 128) {
        float zv = zbuf[(size_t)gp * DIN + i];
        g[i] = ysum[(size_t)gp * DIN + i] * silu(zv);
    }
    __syncthreads();
    if (t < CDIM) {
        float acc = 0.0f;
        for (int dd = 0; dd < DIN; dd++)
            acc = fmaf(g[dd], W_out[dd * CDIM + t], acc);
        out[((size_t)(b * CDIM + t)) * LL + l] = acc;
    }
}

// ---------------- launch ----------------------------------------------------
extern "C" void kernel_launch(void* const* d_in, const int* in_sizes, int n_in,
                              void* d_out, int out_size, void* d_ws, size_t ws_size,
                              hipStream_t stream) {
    const float* x       = (const float*)d_in[0];
    const float* W_in    = (const float*)d_in[1];
    const float* W_conv  = (const float*)d_in[2];
    const float* b_conv  = (const float*)d_in[3];
    const float* W_xproj = (const float*)d_in[4];
    const float* W_dt    = (const float*)d_in[5];
    const float* b_dt    = (const float*)d_in[6];
    const float* A_logs  = (const float*)d_in[7];
    const float* Ds      = (const float*)d_in[8];
    const float* W_out   = (const float*)d_in[9];
    float* out = (float*)d_out;
    float* ws  = (float*)d_ws;

    float* xp   = ws + OFF_XP;      // dead after k_conv; reused as Pbuf
    float* z    = ws + OFF_Z;
    float* xi   = ws + OFF_XI;
    float* dbuf = ws + OFF_DL;
    float* Bbuf = ws + OFF_B;
    float* Cbuf = ws + OFF_C;
    float* ysum = ws + OFF_Y;
    float* hend = ws + OFF_HE;
    float* hin  = ws + OFF_HI;
    float* Pbuf = xp;

    k_inproj<<<(BATCH * LL) / K1_PIX, 384, 0, stream>>>(x, W_in, xp, z);
    k_conv<<<BATCH * LL, DIN, 0, stream>>>(xp, W_conv, b_conv, xi);
    dim3 g3((BATCH * LL) / K3_PIX, NK);
    k_xproj<<<g3, 256, 0, stream>>>(xi, W_xproj, W_dt, b_dt, dbuf, Bbuf, Cbuf, ysum);
    dim3 gs(NCH, NK * BATCH * CGRP);
    k_scanA<<<gs, 256, 0, stream>>>(xi, dbuf, Bbuf, A_logs, Pbuf, hend);
    k_scanB<<<(NK * BATCH * DIN * NST) / 256, 256, 0, stream>>>(Pbuf, hend, hin);
    k_scanC<<<gs, 256, 0, stream>>>(xi, dbuf, Bbuf, Cbuf, A_logs, Ds, hin, ysum);
    k_out<<<BATCH * LL, 128, 0, stream>>>(ysum, z, W_out, out);
}

// Round 4
// 244.723 us; speedup vs baseline: 3.7062x; 1.2224x over previous
//
#include <hip/hip_runtime.h>
#include <math.h>

// ---------------- problem constants ----------------
constexpr int BATCH  = 2;
constexpr int CDIM   = 96;    // model dim
constexpr int HH     = 56;
constexpr int WW     = 56;
constexpr int LL     = HH * WW;          // 3136
constexpr int DIN    = 192;              // d_inner
constexpr int NK     = 4;                // directions
constexpr int NST    = 16;               // d_state
constexpr int RNK    = 6;                // dt_rank
constexpr int EPROJ  = RNK + 2 * NST;    // 38
constexpr int SCH    = 64;               // steps per scan chunk
constexpr int NCH    = LL / SCH;         // 49 chunks
constexpr int CGRP   = DIN / 16;         // 12 channel-groups of 16

// workspace layout (floats)
constexpr size_t SZ_PX   = (size_t)BATCH * LL * DIN;        // 1,204,224
constexpr size_t OFF_XP  = 0;                               // xp; reused as P after conv
constexpr size_t OFF_Z   = OFF_XP + SZ_PX;
constexpr size_t OFF_XI  = OFF_Z  + SZ_PX;
constexpr size_t OFF_DL  = OFF_XI + SZ_PX;                  // delta: K*B*L*192
constexpr size_t SZ_DL   = (size_t)NK * BATCH * LL * DIN;
constexpr size_t OFF_B   = OFF_DL + SZ_DL;                  // B: K*B*L*16
constexpr size_t SZ_BC   = (size_t)NK * BATCH * LL * NST;
constexpr size_t OFF_C   = OFF_B + SZ_BC;
constexpr size_t OFF_Y   = OFF_C + SZ_BC;                   // ysum: B*L*192
constexpr size_t SZ_HS   = (size_t)NK * BATCH * NCH * DIN * NST;  // 1,204,224
constexpr size_t OFF_HE  = OFF_Y + SZ_PX;                   // h_end per chunk
constexpr size_t OFF_HI  = OFF_HE + SZ_HS;                  // h_in  per chunk

__device__ __forceinline__ float silu(float v) {
    return v / (1.0f + __expf(-v));
}

// full 16-lane-row sum via DPP row rotations (VALU only, no LDS pipe).
// After ror 8,4,2,1 adds every lane holds the row sum.
__device__ __forceinline__ float row_reduce16(float p) {
    p += __int_as_float(__builtin_amdgcn_update_dpp(0, __float_as_int(p), 0x128, 0xf, 0xf, true));
    p += __int_as_float(__builtin_amdgcn_update_dpp(0, __float_as_int(p), 0x124, 0xf, 0xf, true));
    p += __int_as_float(__builtin_amdgcn_update_dpp(0, __float_as_int(p), 0x122, 0xf, 0xf, true));
    p += __int_as_float(__builtin_amdgcn_update_dpp(0, __float_as_int(p), 0x121, 0xf, 0xf, true));
    return p;
}

// direction k, sequence position l -> row-major spatial index
__device__ __forceinline__ int seq_to_lr(int k, int l) {
    int q = l / WW;
    int r = l - q * WW;
    if (k == 0) return l;
    if (k == 1) return q * WW + (WW - 1 - r);
    if (k == 2) return r * WW + q;
    return (WW - 1 - r) * WW + q;
}

// direction k, row-major spatial index s -> sequence position (inverse map)
__device__ __forceinline__ int spatial_to_seq(int k, int s) {
    int h = s / WW;
    int w = s - h * WW;
    if (k == 0) return s;
    if (k == 1) return h * WW + (WW - 1 - w);
    if (k == 2) return w * WW + h;
    return w * WW + (WW - 1 - h);
}

// chunk-summary index: [c][kb][d][n], coalesced in (d,n) for pass B
__device__ __forceinline__ size_t hs_idx(int c, int kb, int d, int n) {
    return ((size_t)(c * (NK * BATCH) + kb) * DIN + d) * NST + n;
}

// ---------------- kernel 1: in-projection (x^T @ W_in -> xp, z) --------------
constexpr int K1_PIX = 8;
__global__ __launch_bounds__(384) void k_inproj(
        const float* __restrict__ x, const float* __restrict__ W_in,
        float* __restrict__ xp, float* __restrict__ z) {
    __shared__ float sx[K1_PIX][100];   // padded to break bank conflicts
    int gp0 = blockIdx.x * K1_PIX;      // global pixel = b*LL + l
    int t   = threadIdx.x;
    int b   = gp0 / LL;
    int l0  = gp0 - b * LL;
    for (int i = t; i < K1_PIX * CDIM; i += 384) {
        int p = i % K1_PIX;
        int c = i / K1_PIX;
        sx[p][c] = x[((size_t)(b * CDIM + c)) * LL + l0 + p];
    }
    __syncthreads();
    int e = t;                          // 0..383 output feature
    float acc[K1_PIX];
#pragma unroll
    for (int p = 0; p < K1_PIX; p++) acc[p] = 0.0f;
    for (int c = 0; c < CDIM; c++) {
        float w = W_in[c * (2 * DIN) + e];
#pragma unroll
        for (int p = 0; p < K1_PIX; p++) acc[p] = fmaf(sx[p][c], w, acc[p]);
    }
    if (e < DIN) {
#pragma unroll
        for (int p = 0; p < K1_PIX; p++)
            xp[((size_t)(gp0 + p)) * DIN + e] = acc[p];
    } else {
        int e2 = e - DIN;
#pragma unroll
        for (int p = 0; p < K1_PIX; p++)
            z[((size_t)(gp0 + p)) * DIN + e2] = acc[p];
    }
}

// ---------------- kernel 2: depthwise conv 3x3 + bias + SiLU ----------------
__global__ __launch_bounds__(192) void k_conv(
        const float* __restrict__ xp, const float* __restrict__ Wc,
        const float* __restrict__ bc, float* __restrict__ xi) {
    int gp = blockIdx.x;
    int d  = threadIdx.x;
    int b  = gp / LL;
    int l  = gp - b * LL;
    int h  = l / WW;
    int w  = l - h * WW;
    float acc = bc[d];
#pragma unroll
    for (int dy = -1; dy <= 1; dy++) {
        int hh = h + dy;
        if (hh < 0 || hh >= HH) continue;
#pragma unroll
        for (int dx = -1; dx <= 1; dx++) {
            int ww = w + dx;
            if (ww < 0 || ww >= WW) continue;
            acc = fmaf(xp[((size_t)b * LL + hh * WW + ww) * DIN + d],
                       Wc[d * 9 + (dy + 1) * 3 + (dx + 1)], acc);
        }
    }
    xi[(size_t)gp * DIN + d] = silu(acc);
}

// ------- kernel 3: x-proj (dr,B,C) + delta=softplus(dr@W_dt+b) ---------------
// Also initializes ysum = xi * (sum_k Ds[k]) -- the D*u term evicted from the
// scan. Scatters B/C/delta to direction-k sequence positions.
constexpr int K3_PIX = 16;
__global__ __launch_bounds__(256) void k_xproj(
        const float* __restrict__ xi, const float* __restrict__ W_xproj,
        const float* __restrict__ W_dt, const float* __restrict__ b_dt,
        const float* __restrict__ Ds,
        float* __restrict__ dbuf, float* __restrict__ Bbuf,
        float* __restrict__ Cbuf, float* __restrict__ ysum) {
    __shared__ float v[K3_PIX][DIN];
    __shared__ float drs[K3_PIX][RNK];
    int k   = blockIdx.y;
    int gp0 = blockIdx.x * K3_PIX;
    int b   = gp0 / LL;
    int l0  = gp0 - b * LL;
    int t   = threadIdx.x;
    for (int i = t; i < K3_PIX * DIN; i += 256) {
        int p = i / DIN, d = i % DIN;
        v[p][d] = xi[((size_t)(gp0 + p)) * DIN + d];
    }
    __syncthreads();
    for (int i = t; i < K3_PIX * EPROJ; i += 256) {
        int p = i / EPROJ, e = i % EPROJ;
        const float* wp = W_xproj + (size_t)k * DIN * EPROJ + e;
        float acc = 0.0f;
        for (int d = 0; d < DIN; d++) acc = fmaf(v[p][d], wp[d * EPROJ], acc);
        int ls = spatial_to_seq(k, l0 + p);      // sequence position
        size_t base = ((size_t)(k * BATCH + b)) * LL + ls;
        if (e < RNK)            drs[p][e] = acc;
        else if (e < RNK + NST) Bbuf[base * NST + (e - RNK)] = acc;
        else                    Cbuf[base * NST + (e - RNK - NST)] = acc;
    }
    __syncthreads();
    for (int i = t; i < K3_PIX * DIN; i += 256) {
        int p = i / DIN, d = i % DIN;
        float acc = b_dt[k * DIN + d];
#pragma unroll
        for (int r = 0; r < RNK; r++)
            acc = fmaf(drs[p][r], W_dt[((size_t)k * RNK + r) * DIN + d], acc);
        float sp = (acc > 20.0f) ? acc : log1pf(__expf(acc));
        int ls = spatial_to_seq(k, l0 + p);      // sequence position
        dbuf[(((size_t)(k * BATCH + b)) * LL + ls) * DIN + d] = sp;
        if (k == 0) {
            float dsum = Ds[d] + Ds[DIN + d] + Ds[2 * DIN + d] + Ds[3 * DIN + d];
            ysum[((size_t)(gp0 + p)) * DIN + d] = v[p][d] * dsum;
        }
    }
}

// -------- kernel 4a: chunk-local scan -> per-chunk summary (P, h_end) --------
__global__ __launch_bounds__(256) void k_scanA(
        const float* __restrict__ xi, const float* __restrict__ dbuf,
        const float* __restrict__ Bbuf, const float* __restrict__ A_logs,
        float* __restrict__ Pbuf, float* __restrict__ hend) {
    __shared__ float2 sDU[SCH][16];   // {delta, delta*u}
    __shared__ float  sB1[SCH][16];
    int c   = blockIdx.x;
    int blk = blockIdx.y;
    int k   = blk / (BATCH * CGRP);
    int rem = blk % (BATCH * CGRP);
    int b   = rem / CGRP;
    int cg  = rem % CGRP;
    int d0  = cg * 16;
    int t    = threadIdx.x;
    int lane = t & 63, wave = t >> 6;
    int grp  = lane >> 4, n = lane & 15;
    int ch   = wave * 4 + grp;
    int d    = d0 + ch;
    float A = -__expf(A_logs[((size_t)(k * DIN + d)) * NST + n]);
    size_t sbase = ((size_t)(k * BATCH + b)) * LL;
    const float* dp = dbuf + sbase * DIN + d0;
    const float* bp = Bbuf + sbase * NST;
    const float* up = xi   + (size_t)b * LL * DIN;
    int l0 = c * SCH;
    for (int i = t; i < SCH * 16; i += 256) {
        int s = i >> 4, cc = i & 15;
        int l = l0 + s;
        int lr = seq_to_lr(k, l);
        float dlt = dp[(size_t)l * DIN + cc];
        float u   = up[(size_t)lr * DIN + d0 + cc];
        sDU[s][cc] = make_float2(dlt, dlt * u);
        sB1[s][cc] = bp[(size_t)l * NST + cc];
    }
    __syncthreads();
    float h = 0.0f, P = 1.0f;
#pragma unroll 8
    for (int s = 0; s < SCH; s++) {
        float2 du = sDU[s][ch];
        float dA  = __expf(du.x * A);
        h = fmaf(dA, h, du.y * sB1[s][n]);
        P *= dA;
    }
    size_t idx = hs_idx(c, k * BATCH + b, d, n);
    Pbuf[idx] = P;
    hend[idx] = h;
}

// -------- kernel 4b: sequential combine over 49 chunk summaries --------------
__global__ __launch_bounds__(256) void k_scanB(
        const float* __restrict__ Pbuf, const float* __restrict__ hend,
        float* __restrict__ hin) {
    int tid = blockIdx.x * 256 + threadIdx.x;       // over K*B*DIN*NST = 24576
    int kb  = tid / (DIN * NST);
    int dn  = tid % (DIN * NST);
    float h = 0.0f;
    for (int c = 0; c < NCH; c++) {
        size_t idx = ((size_t)(c * (NK * BATCH) + kb)) * (DIN * NST) + dn;
        hin[idx] = h;
        h = fmaf(Pbuf[idx], h, hend[idx]);
    }
}

// -------- kernel 4c: chunk-local scan with true h_in; emit y -----------------
__global__ __launch_bounds__(256) void k_scanC(
        const float* __restrict__ xi, const float* __restrict__ dbuf,
        const float* __restrict__ Bbuf, const float* __restrict__ Cbuf,
        const float* __restrict__ A_logs, const float* __restrict__ hin,
        float* __restrict__ ysum) {
    __shared__ float2 sDU[SCH][16];   // {delta, delta*u}
    __shared__ float2 sBC[SCH][16];   // {B, C}
    __shared__ float  sY[SCH][16];
    int c   = blockIdx.x;
    int blk = blockIdx.y;
    int k   = blk / (BATCH * CGRP);
    int rem = blk % (BATCH * CGRP);
    int b   = rem / CGRP;
    int cg  = rem % CGRP;
    int d0  = cg * 16;
    int t    = threadIdx.x;
    int lane = t & 63, wave = t >> 6;
    int grp  = lane >> 4, n = lane & 15;
    int ch   = wave * 4 + grp;
    int d    = d0 + ch;
    float A = -__expf(A_logs[((size_t)(k * DIN + d)) * NST + n]);
    size_t sbase = ((size_t)(k * BATCH + b)) * LL;
    const float* dp = dbuf + sbase * DIN + d0;
    const float* bp = Bbuf + sbase * NST;
    const float* cp = Cbuf + sbase * NST;
    const float* up = xi   + (size_t)b * LL * DIN;
    float*       yp = ysum + (size_t)b * LL * DIN;
    int l0 = c * SCH;
    for (int i = t; i < SCH * 16; i += 256) {
        int s = i >> 4, cc = i & 15;
        int l = l0 + s;
        int lr = seq_to_lr(k, l);
        float dlt = dp[(size_t)l * DIN + cc];
        float u   = up[(size_t)lr * DIN + d0 + cc];
        sDU[s][cc] = make_float2(dlt, dlt * u);
        sBC[s][cc] = make_float2(bp[(size_t)l * NST + cc],
                                 cp[(size_t)l * NST + cc]);
    }
    float h = hin[hs_idx(c, k * BATCH + b, d, n)];
    __syncthreads();
#pragma unroll 4
    for (int s = 0; s < SCH; s++) {
        float2 du = sDU[s][ch];
        float2 bc = sBC[s][n];
        float dA  = __expf(du.x * A);
        h = fmaf(dA, h, du.y * bc.x);
        float p = row_reduce16(h * bc.y);
        if (n == 0) sY[s][ch] = p;
    }
    __syncthreads();
    for (int i = t; i < SCH * 16; i += 256) {
        int s = i >> 4, cc = i & 15;
        int lr = seq_to_lr(k, l0 + s);
        atomicAdd(&yp[(size_t)lr * DIN + d0 + cc], sY[s][cc]);
    }
}

// ---------------- kernel 5: gate + out-projection ---------------------------
// 8 pixels per block; LDS-transposed stores for 8-dword coalesced segments.
constexpr int K5_PIX = 8;
__global__ __launch_bounds__(192) void k_out(
        const float* __restrict__ ysum, const float* __restrict__ zbuf,
        const float* __restrict__ W_out, float* __restrict__ out) {
    __shared__ float g[K5_PIX][DIN];       // 6 KB
    __shared__ float so[CDIM][K5_PIX];     // 3 KB
    int gp0 = blockIdx.x * K5_PIX;
    int b   = gp0 / LL;
    int l0  = gp0 - b * LL;
    int t   = threadIdx.x;
    for (int i = t; i < K5_PIX * DIN; i += 192) {
        int p = i / DIN, dd = i % DIN;
        size_t idx = (size_t)(gp0 + p) * DIN + dd;
        g[p][dd] = ysum[idx] * silu(zbuf[idx]);
    }
    __syncthreads();
    int f    = t % CDIM;        // output feature
    int half = t / CDIM;        // 0 or 1: which 4 pixels
    float acc[4] = {0.f, 0.f, 0.f, 0.f};
    for (int dd = 0; dd < DIN; dd++) {
        float wv = W_out[dd * CDIM + f];
#pragma unroll
        for (int p = 0; p < 4; p++)
            acc[p] = fmaf(g[half * 4 + p][dd], wv, acc[p]);
    }
#pragma unroll
    for (int p = 0; p < 4; p++) so[f][half * 4 + p] = acc[p];
    __syncthreads();
    for (int i = t; i < CDIM * K5_PIX; i += 192) {
        int f2 = i / K5_PIX, p2 = i % K5_PIX;
        out[((size_t)(b * CDIM + f2)) * LL + l0 + p2] = so[f2][p2];
    }
}

// ---------------- launch ----------------------------------------------------
extern "C" void kernel_launch(void* const* d_in, const int* in_sizes, int n_in,
                              void* d_out, int out_size, void* d_ws, size_t ws_size,
                              hipStream_t stream) {
    const float* x       = (const float*)d_in[0];
    const float* W_in    = (const float*)d_in[1];
    const float* W_conv  = (const float*)d_in[2];
    const float* b_conv  = (const float*)d_in[3];
    const float* W_xproj = (const float*)d_in[4];
    const float* W_dt    = (const float*)d_in[5];
    const float* b_dt    = (const float*)d_in[6];
    const float* A_logs  = (const float*)d_in[7];
    const float* Ds      = (const float*)d_in[8];
    const float* W_out   = (const float*)d_in[9];
    float* out = (float*)d_out;
    float* ws  = (float*)d_ws;

    float* xp   = ws + OFF_XP;      // dead after k_conv; reused as Pbuf
    float* z    = ws + OFF_Z;
    float* xi   = ws + OFF_XI;
    float* dbuf = ws + OFF_DL;
    float* Bbuf = ws + OFF_B;
    float* Cbuf = ws + OFF_C;
    float* ysum = ws + OFF_Y;
    float* hend = ws + OFF_HE;
    float* hin  = ws + OFF_HI;
    float* Pbuf = xp;

    k_inproj<<<(BATCH * LL) / K1_PIX, 384, 0, stream>>>(x, W_in, xp, z);
    k_conv<<<BATCH * LL, DIN, 0, stream>>>(xp, W_conv, b_conv, xi);
    dim3 g3((BATCH * LL) / K3_PIX, NK);
    k_xproj<<<g3, 256, 0, stream>>>(xi, W_xproj, W_dt, b_dt, Ds, dbuf, Bbuf, Cbuf, ysum);
    dim3 gs(NCH, NK * BATCH * CGRP);
    k_scanA<<<gs, 256, 0, stream>>>(xi, dbuf, Bbuf, A_logs, Pbuf, hend);
    k_scanB<<<(NK * BATCH * DIN * NST) / 256, 256, 0, stream>>>(Pbuf, hend, hin);
    k_scanC<<<gs, 256, 0, stream>>>(xi, dbuf, Bbuf, Cbuf, A_logs, hin, ysum);
    k_out<<<(BATCH * LL) / K5_PIX, 192, 0, stream>>>(ysum, z, W_out, out);
}